// Round 1
// baseline (23754.836 us; speedup 1.0000x reference)
//
#include <hip/hip_runtime.h>
#include <math.h>

#define BATCH 128
#define CCH 5
#define SEQ 512
#define UNITS 256
#define RU 512

__device__ __forceinline__ float sigmoidf_(float v) {
    return 1.0f / (1.0f + __expf(-v));
}

// ---------------------------------------------------------------------------
// Encoder: fwd+bwd masked LSTM. 128 blocks: blocks 0..63 fwd (batch pairs),
// 64..127 bwd. Each block owns 2 batch elements, runs all 512 steps.
// Writes enc[b][s][0:256] (fwd) or enc[b][s][256:512] (bwd).
// ---------------------------------------------------------------------------
__global__ __launch_bounds__(1024)
void encoder_kernel(const float* __restrict__ x,
                    const float* __restrict__ Wf_k, const float* __restrict__ Wf_r,
                    const float* __restrict__ bf,
                    const float* __restrict__ Wb_k, const float* __restrict__ Wb_r,
                    const float* __restrict__ bb,
                    float* __restrict__ enc)
{
    const int bid  = blockIdx.x;
    const int dir  = bid >> 6;          // 0 = fwd, 1 = bwd
    const int pair = bid & 63;
    const int b0 = pair * 2, b1 = b0 + 1;
    const float* __restrict__ Wk   = dir ? Wb_k : Wf_k;
    const float* __restrict__ Wr   = dir ? Wb_r : Wf_r;
    const float* __restrict__ bias = dir ? bb : bf;
    const int off = dir ? UNITS : 0;

    __shared__ float WkL[CCH][1024];
    __shared__ float biasL[1024];
    __shared__ float __align__(16) hL[2][UNITS];
    __shared__ float __align__(16) cL[2][UNITS];
    __shared__ float zL[2][1024];
    __shared__ float xL[2][CCH];
    __shared__ int   mL[2];

    const int tid = threadIdx.x;
    #pragma unroll
    for (int c = 0; c < CCH; ++c) WkL[c][tid] = Wk[c * 1024 + tid];
    biasL[tid] = bias[tid];
    if (tid < 2 * UNITS) {
        ((float*)hL)[tid] = 0.0f;
        ((float*)cL)[tid] = 0.0f;
    }
    __syncthreads();

    const float* __restrict__ wrp = Wr + tid;

    for (int t = 0; t < SEQ; ++t) {
        const int ts = dir ? (SEQ - 1 - t) : t;
        // load x_t (feature 0) and mask (feature 2 of channel 0)
        if (tid < 10) {
            int g = tid / CCH, c = tid % CCH;
            int b = g ? b1 : b0;
            xL[g][c] = x[((size_t)(b * CCH + c) * SEQ + ts) * 3 + 0];
        } else if (tid < 12) {
            int g = tid - 10;
            int b = g ? b1 : b0;
            mL[g] = (x[((size_t)(b * CCH + 0) * SEQ + ts) * 3 + 2] != 0.0f);
        }
        __syncthreads();

        // z_j for both batches of the pair
        float z0 = biasL[tid];
        float z1 = z0;
        #pragma unroll
        for (int c = 0; c < CCH; ++c) {
            float wk = WkL[c][tid];
            z0 = fmaf(xL[0][c], wk, z0);
            z1 = fmaf(xL[1][c], wk, z1);
        }
        #pragma unroll 4
        for (int k = 0; k < UNITS; k += 4) {
            float4 ha = *reinterpret_cast<const float4*>(&hL[0][k]);
            float4 hb = *reinterpret_cast<const float4*>(&hL[1][k]);
            float w0 = wrp[(k + 0) * 1024];
            float w1 = wrp[(k + 1) * 1024];
            float w2 = wrp[(k + 2) * 1024];
            float w3 = wrp[(k + 3) * 1024];
            z0 = fmaf(ha.x, w0, z0); z1 = fmaf(hb.x, w0, z1);
            z0 = fmaf(ha.y, w1, z0); z1 = fmaf(hb.y, w1, z1);
            z0 = fmaf(ha.z, w2, z0); z1 = fmaf(hb.z, w2, z1);
            z0 = fmaf(ha.w, w3, z0); z1 = fmaf(hb.w, w3, z1);
        }
        zL[0][tid] = z0;
        zL[1][tid] = z1;
        __syncthreads();

        // cell update (512 threads: 2 batches x 256 units)
        if (tid < 2 * UNITS) {
            int g = tid >> 8, uu = tid & (UNITS - 1);
            float iv = zL[g][uu];
            float fv = zL[g][uu + UNITS];
            float gv = zL[g][uu + 2 * UNITS];
            float ov = zL[g][uu + 3 * UNITS];
            float cn = sigmoidf_(fv) * cL[g][uu] + sigmoidf_(iv) * tanhf(gv);
            float hn = sigmoidf_(ov) * tanhf(cn);
            float h2, c2;
            if (mL[g]) { h2 = hn; c2 = cn; }
            else       { h2 = hL[g][uu]; c2 = cL[g][uu]; }
            hL[g][uu] = h2;
            cL[g][uu] = c2;
            int b = g ? b1 : b0;
            enc[((size_t)b * SEQ + ts) * RU + off + uu] = h2;
        }
        __syncthreads();
    }
}

// ---------------------------------------------------------------------------
// Attention precompute: alpha = softmax(enc @ We + b_attn) is constant over
// decoder time (softmax is invariant to the per-batch scalar x_t@Wx shift).
// Compute attn = alpha @ enc once, plus hidden0, x0 and the constant part of
// the dense output. One block per batch.
// ---------------------------------------------------------------------------
__global__ __launch_bounds__(256)
void attn_kernel(const float* __restrict__ enc,
                 const float* __restrict__ W_attn, const float* __restrict__ b_attn,
                 const float* __restrict__ W_dense, const float* __restrict__ b_dense,
                 const float* __restrict__ x,
                 float* __restrict__ attn_ws, float* __restrict__ hidden_ws,
                 float* __restrict__ xbuf, float* __restrict__ xconst)
{
    const int b = blockIdx.x;
    const int tid = threadIdx.x;
    const int lane = tid & 63;
    const int wv = tid >> 6;

    __shared__ float WeL[RU];
    __shared__ float scoresL[SEQ];
    __shared__ float red[256];
    __shared__ float attnL[RU];

    WeL[tid]       = W_attn[CCH + tid];
    WeL[tid + 256] = W_attn[CCH + tid + 256];
    __syncthreads();

    const float* __restrict__ encb = enc + (size_t)b * SEQ * RU;
    const float batt = b_attn[0];

    // scores[s] = enc[b,s,:] . We + b_attn   (one wave per s)
    for (int s = wv; s < SEQ; s += 4) {
        const float* row = encb + (size_t)s * RU;
        float p = 0.0f;
        #pragma unroll
        for (int i = 0; i < 8; ++i) {
            int d = lane * 8 + i;
            p = fmaf(row[d], WeL[d], p);
        }
        #pragma unroll
        for (int o = 32; o; o >>= 1) p += __shfl_xor(p, o);
        if (lane == 0) scoresL[s] = p + batt;
    }
    __syncthreads();

    // softmax over 512 scores
    float m = fmaxf(scoresL[tid], scoresL[tid + 256]);
    red[tid] = m;
    __syncthreads();
    for (int st = 128; st; st >>= 1) {
        if (tid < st) red[tid] = fmaxf(red[tid], red[tid + st]);
        __syncthreads();
    }
    const float mx = red[0];
    __syncthreads();
    float e0 = __expf(scoresL[tid] - mx);
    float e1 = __expf(scoresL[tid + 256] - mx);
    red[tid] = e0 + e1;
    __syncthreads();
    for (int st = 128; st; st >>= 1) {
        if (tid < st) red[tid] += red[tid + st];
        __syncthreads();
    }
    const float sinv = 1.0f / red[0];
    __syncthreads();
    scoresL[tid]       = e0 * sinv;   // alpha
    scoresL[tid + 256] = e1 * sinv;
    __syncthreads();

    // attn[d] = sum_s alpha[s] * enc[b,s,d]
    float a0 = 0.0f, a1 = 0.0f;
    for (int s = 0; s < SEQ; ++s) {
        float al = scoresL[s];
        a0 = fmaf(al, encb[(size_t)s * RU + tid], a0);
        a1 = fmaf(al, encb[(size_t)s * RU + tid + 256], a1);
    }
    attn_ws[(size_t)b * RU + tid]       = a0;
    attn_ws[(size_t)b * RU + tid + 256] = a1;
    attnL[tid] = a0;
    attnL[tid + 256] = a1;
    hidden_ws[(size_t)b * RU + tid]       = encb[(size_t)(SEQ - 1) * RU + tid];
    hidden_ws[(size_t)b * RU + tid + 256] = encb[(size_t)(SEQ - 1) * RU + tid + 256];
    if (tid < CCH) xbuf[b * CCH + tid] = x[((size_t)(b * CCH + tid) * SEQ + 0) * 3];
    __syncthreads();

    // xconst[c] = b_dense[c] + sum_d attn[d] * W_dense[RU+d, c]
    if (tid < CCH) {
        float acc = b_dense[tid];
        for (int d = 0; d < RU; ++d)
            acc = fmaf(attnL[d], W_dense[(RU + d) * CCH + tid], acc);
        xconst[b * CCH + tid] = acc;
    }
}

// ---------------------------------------------------------------------------
// Decoder: 511 recurrent steps; attn (= cell c input) is constant. 64 blocks,
// each owns a batch pair; 1024 threads compute 2048 z outputs (2 j each).
// ---------------------------------------------------------------------------
__global__ __launch_bounds__(1024)
void decoder_kernel(const float* __restrict__ Wd_k, const float* __restrict__ Wd_r,
                    const float* __restrict__ bd,
                    const float* __restrict__ W_dense,
                    const float* __restrict__ attn_ws, const float* __restrict__ hidden_ws,
                    const float* __restrict__ xbuf, const float* __restrict__ xconst,
                    float* __restrict__ out)
{
    const int gblk = blockIdx.x;
    const int b0 = gblk * 2, b1 = b0 + 1;
    const int tid = threadIdx.x;
    const int lane = tid & 63;
    const int wv = tid >> 6;

    __shared__ float __align__(16) hL[2][RU];
    __shared__ float attnL[2][RU];
    __shared__ float zL[2][2048];
    __shared__ float xL[2][CCH];
    __shared__ float xcL[2][CCH];

    if (tid < RU) {
        hL[0][tid]    = hidden_ws[(size_t)b0 * RU + tid];
        hL[1][tid]    = hidden_ws[(size_t)b1 * RU + tid];
        attnL[0][tid] = attn_ws[(size_t)b0 * RU + tid];
        attnL[1][tid] = attn_ws[(size_t)b1 * RU + tid];
    }
    if (tid < 2 * CCH) {
        int g = tid / CCH, c = tid % CCH;
        int b = g ? b1 : b0;
        xL[g][c]  = xbuf[b * CCH + c];
        xcL[g][c] = xconst[b * CCH + c];
    }
    __syncthreads();

    const int j0 = tid;
    const int j1 = tid + 1024;
    const float* __restrict__ wr = Wd_r + j0;

    for (int t = 0; t < SEQ - 1; ++t) {
        float za0 = bd[j0], za1 = bd[j1];   // batch 0
        float zb0 = za0,    zb1 = za1;      // batch 1
        #pragma unroll
        for (int c = 0; c < CCH; ++c) {
            float wk0 = Wd_k[c * 2048 + j0];
            float wk1 = Wd_k[c * 2048 + j1];
            float xa = xL[0][c], xb = xL[1][c];
            za0 = fmaf(xa, wk0, za0); zb0 = fmaf(xb, wk0, zb0);
            za1 = fmaf(xa, wk1, za1); zb1 = fmaf(xb, wk1, zb1);
        }
        #pragma unroll 2
        for (int k = 0; k < RU; k += 4) {
            float4 ha = *reinterpret_cast<const float4*>(&hL[0][k]);
            float4 hb = *reinterpret_cast<const float4*>(&hL[1][k]);
            float w00 = wr[(size_t)(k + 0) * 2048], w01 = wr[(size_t)(k + 0) * 2048 + 1024];
            float w10 = wr[(size_t)(k + 1) * 2048], w11 = wr[(size_t)(k + 1) * 2048 + 1024];
            float w20 = wr[(size_t)(k + 2) * 2048], w21 = wr[(size_t)(k + 2) * 2048 + 1024];
            float w30 = wr[(size_t)(k + 3) * 2048], w31 = wr[(size_t)(k + 3) * 2048 + 1024];
            za0 = fmaf(ha.x, w00, za0); zb0 = fmaf(hb.x, w00, zb0);
            za1 = fmaf(ha.x, w01, za1); zb1 = fmaf(hb.x, w01, zb1);
            za0 = fmaf(ha.y, w10, za0); zb0 = fmaf(hb.y, w10, zb0);
            za1 = fmaf(ha.y, w11, za1); zb1 = fmaf(hb.y, w11, zb1);
            za0 = fmaf(ha.z, w20, za0); zb0 = fmaf(hb.z, w20, zb0);
            za1 = fmaf(ha.z, w21, za1); zb1 = fmaf(hb.z, w21, zb1);
            za0 = fmaf(ha.w, w30, za0); zb0 = fmaf(hb.w, w30, zb0);
            za1 = fmaf(ha.w, w31, za1); zb1 = fmaf(hb.w, w31, zb1);
        }
        zL[0][j0] = za0; zL[0][j1] = za1;
        zL[1][j0] = zb0; zL[1][j1] = zb1;
        __syncthreads();

        // cell update: 1024 threads = 2 batches x 512 units
        {
            int g = tid >> 9, uu = tid & (RU - 1);
            float iv = zL[g][uu];
            float fv = zL[g][uu + 512];
            float gv = zL[g][uu + 1024];
            float ov = zL[g][uu + 1536];
            float at = attnL[g][uu];
            float cn = sigmoidf_(fv) * at + sigmoidf_(iv) * tanhf(gv);
            float hn = sigmoidf_(ov) * tanhf(cn);
            hL[g][uu] = hn;
        }
        __syncthreads();

        // x_new[g][c] = xconst + h_new . W_dense[:RU, c]  (10 wave-reductions)
        if (wv < 2 * CCH) {
            int g = wv / CCH, c = wv % CCH;
            float p = 0.0f;
            #pragma unroll
            for (int it = 0; it < RU / 64; ++it) {
                int u = lane + it * 64;
                p = fmaf(hL[g][u], W_dense[u * CCH + c], p);
            }
            #pragma unroll
            for (int o = 32; o; o >>= 1) p += __shfl_xor(p, o);
            if (lane == 0) {
                float xn = p + xcL[g][c];
                xL[g][c] = xn;
                int b = g ? b1 : b0;
                out[(size_t)(b * CCH + c) * (SEQ - 1) + t] = xn;
            }
        }
        __syncthreads();
    }
}

// ---------------------------------------------------------------------------
extern "C" void kernel_launch(void* const* d_in, const int* in_sizes, int n_in,
                              void* d_out, int out_size, void* d_ws, size_t ws_size,
                              hipStream_t stream)
{
    const float* x       = (const float*)d_in[0];
    const float* Wf_k    = (const float*)d_in[1];
    const float* Wf_r    = (const float*)d_in[2];
    const float* bf      = (const float*)d_in[3];
    const float* Wb_k    = (const float*)d_in[4];
    const float* Wb_r    = (const float*)d_in[5];
    const float* bb      = (const float*)d_in[6];
    const float* Wd_k    = (const float*)d_in[7];
    const float* Wd_r    = (const float*)d_in[8];
    const float* bd      = (const float*)d_in[9];
    const float* W_attn  = (const float*)d_in[10];
    const float* b_attn  = (const float*)d_in[11];
    const float* W_dense = (const float*)d_in[12];
    const float* b_dense = (const float*)d_in[13];
    float* out = (float*)d_out;

    float* ws     = (float*)d_ws;
    float* enc    = ws;                                   // B*S*RU = 33554432 floats
    float* attn   = ws + (size_t)BATCH * SEQ * RU;        // B*RU
    float* hidden = attn + (size_t)BATCH * RU;            // B*RU
    float* xbuf   = hidden + (size_t)BATCH * RU;          // B*C
    float* xconst = xbuf + (size_t)BATCH * CCH;           // B*C

    encoder_kernel<<<128, 1024, 0, stream>>>(x, Wf_k, Wf_r, bf, Wb_k, Wb_r, bb, enc);
    attn_kernel<<<BATCH, 256, 0, stream>>>(enc, W_attn, b_attn, W_dense, b_dense, x,
                                           attn, hidden, xbuf, xconst);
    decoder_kernel<<<64, 1024, 0, stream>>>(Wd_k, Wd_r, bd, W_dense,
                                            attn, hidden, xbuf, xconst, out);
}